// Round 4
// baseline (2430.589 us; speedup 1.0000x reference)
//
#include <hip/hip_runtime.h>

typedef unsigned int uint_t;

#define BB 64
#define TT 1024

__device__ __forceinline__ float sigm(float x) { return 1.f / (1.f + __expf(-x)); }
__device__ __forceinline__ float tanh_f(float x) { float e = __expf(2.f * x); return 1.f - 2.f / (e + 1.f); }
__device__ __forceinline__ int finitef(float x) { return (x == x) && (fabsf(x) < 1e30f); }

// x feature j of token (b,t): [e_i(0..9) | e_j(10..19) | rbf(20..29)]
__device__ __forceinline__ float feat(int b, int t, int j,
                                      const int* atom_idx, const float* bond_dist,
                                      const float* emb) {
  int ii = atom_idx[(b * TT + t) * 2 + 0];
  if (j < 10) {
    return ii ? emb[ii * 10 + j] : 0.f;
  } else if (j < 20) {
    int jj = atom_idx[(b * TT + t) * 2 + 1];
    return jj ? emb[jj * 10 + (j - 10)] : 0.f;
  } else {
    float d = bond_dist[b * TT + t];
    float c = (float)(j - 19);
    float df = c - d;
    return ii ? __expf(-df * df) : 0.f;
  }
}

// ---------------- xw0 = x @ w_ih0.T + b_ih0  (time-parallel, K=30, G=192) ----------------
// weights read wave-uniformly from global (scalarizable); activations in padded LDS.
extern "C" __global__ void __launch_bounds__(256)
k_xw0(const int* atom_idx, const float* bond_dist, const float* emb,
      const float* w_ih0, const float* b_ih0, float* xw0) {
  int b  = blockIdx.x >> 4;
  int t0 = (blockIdx.x & 15) << 6;
  int tid = threadIdx.x;
  __shared__ float xt[64 * 31];
  for (int i = tid; i < 64 * 30; i += 256) {
    int r = i / 30, j = i % 30;
    xt[r * 31 + j] = feat(b, t0 + r, j, atom_idx, bond_dist, emb);
  }
  __syncthreads();
  // L over 64*192 outputs: g = L>>6 (wave-uniform), r = L&63
  for (int L = tid; L < 64 * 192; L += 256) {
    int g = L >> 6, r = L & 63;
    const float* wr = w_ih0 + g * 30;
    const float* ar = &xt[r * 31];
    float acc = b_ih0[g];
    #pragma unroll
    for (int c = 0; c < 30; ++c) acc += wr[c] * ar[c];
    xw0[((size_t)b * TT + t0 + r) * 192 + g] = acc;
  }
}

// ---------------- generic (64 rows) x (G x 64) GEMM: out[r][g] = act[r] . w[g] + bias[g] ----------------
__device__ __forceinline__ void gemm64(const float* __restrict__ act_g,   // 64 rows x 64, global
                                       const float* __restrict__ w,      // G x 64, global (row-major)
                                       const float* __restrict__ bias,   // G
                                       float* al,                        // LDS 64*65
                                       int G, int tid,
                                       float* out, int out_rstride, size_t out_base) {
  for (int i = tid; i < 64 * 64; i += 256) {
    int r = i >> 6, c = i & 63;
    al[r * 65 + c] = act_g[r * 64 + c];
  }
  __syncthreads();
  for (int L = tid; L < 64 * G; L += 256) {
    int g = L >> 6, r = L & 63;
    const float* wr = w + (size_t)g * 64;
    const float* ar = &al[r * 65];
    float acc = bias[g];
    #pragma unroll
    for (int c = 0; c < 64; ++c) acc += wr[c] * ar[c];
    out[out_base + (size_t)r * out_rstride + g] = acc;
  }
}

// ---------------- xw1 = h0seq @ w_ih1.T + b_ih1 (K=64, G=192) ----------------
extern "C" __global__ void __launch_bounds__(256)
k_xw1(const float* h0seq, const float* w_ih1, const float* b_ih1, float* xw1) {
  int b  = blockIdx.x >> 4;
  int t0 = (blockIdx.x & 15) << 6;
  __shared__ float al[64 * 65];
  gemm64(h0seq + ((size_t)b * TT + t0) * 64, w_ih1, b_ih1, al, 192, threadIdx.x,
         xw1, 192, ((size_t)b * TT + t0) * 192);
}

// ---------------- sequential GRU recurrence (shared by both layers; xw precomputed) ----------------
extern "C" __global__ void __launch_bounds__(256)
k_gruseq(const float* xw, const float* w_hh, const float* b_hh, float* hout) {
  int b = blockIdx.x;
  int t = threadIdx.x;
  __shared__ __align__(16) float h[64];
  __shared__ float gh[192];
  __shared__ float xwb[2][192];
  float w[64];
  float bias = 0.f;
  if (t < 192) {
    #pragma unroll
    for (int k = 0; k < 64; ++k) w[k] = w_hh[t * 64 + k];
    bias = b_hh[t];
  }
  if (t < 64) h[t] = 0.f;
  if (t >= 192) {
    int j = t - 192;
    const float* xr = xw + (size_t)b * TT * 192;
    xwb[0][j]       = xr[j];
    xwb[0][64 + j]  = xr[64 + j];
    xwb[0][128 + j] = xr[128 + j];
  }
  __syncthreads();
  for (int s = 0; s < TT; ++s) {
    if (t < 192) {
      float a0 = bias, a1 = 0.f, a2 = 0.f, a3 = 0.f;
      const float4* h4 = (const float4*)h;
      #pragma unroll
      for (int i = 0; i < 16; ++i) {
        float4 hv = h4[i];
        a0 += hv.x * w[4 * i + 0];
        a1 += hv.y * w[4 * i + 1];
        a2 += hv.z * w[4 * i + 2];
        a3 += hv.w * w[4 * i + 3];
      }
      gh[t] = (a0 + a1) + (a2 + a3);
    } else if (s + 1 < TT) {
      int j = t - 192;
      const float* xr = xw + ((size_t)b * TT + (s + 1)) * 192;
      int nb = (s + 1) & 1;
      xwb[nb][j]       = xr[j];
      xwb[nb][64 + j]  = xr[64 + j];
      xwb[nb][128 + j] = xr[128 + j];
    }
    __syncthreads();
    if (t < 64) {
      const float* xc = xwb[s & 1];
      float xr_ = xc[t], xz = xc[64 + t], xn = xc[128 + t];
      float hr = gh[t], hz = gh[64 + t], hn = gh[128 + t];
      float r = sigm(xr_ + hr);
      float z = sigm(xz + hz);
      float n = tanh_f(xn + r * hn);
      float hv = (1.f - z) * n + z * h[t];
      h[t] = hv;
      hout[((size_t)b * TT + s) * 64 + t] = hv;
    }
    __syncthreads();
  }
}

// ---------------- MHA1 qkv projection (K=64, G=192) -> head-major f32 ----------------
extern "C" __global__ void __launch_bounds__(256)
k_qkv(const float* g1, const float* in_w1, const float* in_b1,
      float* q1, float* k1, float* v1) {
  int b  = blockIdx.x >> 4;
  int t0 = (blockIdx.x & 15) << 6;
  int tid = threadIdx.x;
  __shared__ float al[64 * 65];
  const float* act = g1 + ((size_t)b * TT + t0) * 64;
  for (int i = tid; i < 64 * 64; i += 256) {
    int r = i >> 6, c = i & 63;
    al[r * 65 + c] = act[r * 64 + c];
  }
  __syncthreads();
  for (int L = tid; L < 64 * 192; L += 256) {
    int g = L >> 6, r = L & 63;
    const float* wr = in_w1 + (size_t)g * 64;
    const float* ar = &al[r * 65];
    float acc = in_b1[g];
    #pragma unroll
    for (int c = 0; c < 64; ++c) acc += wr[c] * ar[c];
    int p = g / 64;            // 0=q 1=k 2=v
    int rem = g - p * 64;
    int hd = rem >> 5, d = rem & 31;
    float* outp = (p == 0) ? q1 : ((p == 1) ? k1 : v1);
    outp[(((size_t)b * 2 + hd) * TT + t0 + r) * 32 + d] = acc;
  }
}

// ---------------- MHA1 flash attention (VALU, online softmax), f32 ----------------
extern "C" __global__ void __launch_bounds__(256)
k_attn(const float* q1, const float* k1, const float* v1, float* attnO) {
  int gid = blockIdx.x;
  int b  = gid >> 3;
  int h  = (gid >> 2) & 1;
  int qb = gid & 3;
  int tid = threadIdx.x;
  int tq = qb * 256 + tid;
  __shared__ __align__(16) float Kt[64 * 32];
  __shared__ __align__(16) float Vt[64 * 32];
  float q[32], o[32];
  const float* qp = q1 + (((size_t)b * 2 + h) * TT + tq) * 32;
  #pragma unroll
  for (int i = 0; i < 8; ++i) {
    float4 v = ((const float4*)qp)[i];
    q[4 * i] = v.x; q[4 * i + 1] = v.y; q[4 * i + 2] = v.z; q[4 * i + 3] = v.w;
  }
  #pragma unroll
  for (int i = 0; i < 32; ++i) o[i] = 0.f;
  float m = -1e30f, l = 0.f;
  const float scale = 0.17677669529663687f;   // 1/sqrt(32)
  const float4* kb = (const float4*)(k1 + ((size_t)b * 2 + h) * TT * 32);
  const float4* vb = (const float4*)(v1 + ((size_t)b * 2 + h) * TT * 32);
  for (int kt = 0; kt < TT; kt += 64) {
    __syncthreads();
    ((float4*)Kt)[tid]       = kb[kt * 8 + tid];
    ((float4*)Kt)[tid + 256] = kb[kt * 8 + tid + 256];
    ((float4*)Vt)[tid]       = vb[kt * 8 + tid];
    ((float4*)Vt)[tid + 256] = vb[kt * 8 + tid + 256];
    __syncthreads();
    #pragma unroll 1
    for (int c0 = 0; c0 < 64; c0 += 8) {
      float sv[8];
      #pragma unroll
      for (int j = 0; j < 8; ++j) {
        const float4* kr = (const float4*)&Kt[(c0 + j) * 32];
        float a0 = 0, a1 = 0, a2 = 0, a3 = 0;
        #pragma unroll
        for (int i = 0; i < 8; ++i) {
          float4 kv = kr[i];
          a0 += q[4 * i] * kv.x; a1 += q[4 * i + 1] * kv.y;
          a2 += q[4 * i + 2] * kv.z; a3 += q[4 * i + 3] * kv.w;
        }
        sv[j] = ((a0 + a1) + (a2 + a3)) * scale;
      }
      float cm = sv[0];
      #pragma unroll
      for (int j = 1; j < 8; ++j) cm = fmaxf(cm, sv[j]);
      float mnew = fmaxf(m, cm);
      float alpha = __expf(m - mnew);
      float ps = 0.f;
      #pragma unroll
      for (int j = 0; j < 8; ++j) { sv[j] = __expf(sv[j] - mnew); ps += sv[j]; }
      l = l * alpha + ps;
      m = mnew;
      #pragma unroll
      for (int i = 0; i < 8; ++i) {
        float4 acc;
        acc.x = o[4 * i] * alpha; acc.y = o[4 * i + 1] * alpha;
        acc.z = o[4 * i + 2] * alpha; acc.w = o[4 * i + 3] * alpha;
        #pragma unroll
        for (int j = 0; j < 8; ++j) {
          float4 vv = *(const float4*)&Vt[(c0 + j) * 32 + 4 * i];
          acc.x += sv[j] * vv.x; acc.y += sv[j] * vv.y;
          acc.z += sv[j] * vv.z; acc.w += sv[j] * vv.w;
        }
        o[4 * i] = acc.x; o[4 * i + 1] = acc.y; o[4 * i + 2] = acc.z; o[4 * i + 3] = acc.w;
      }
    }
  }
  float inv = 1.f / l;
  float* op = attnO + ((size_t)b * TT + tq) * 64 + h * 32;
  #pragma unroll
  for (int i = 0; i < 8; ++i) {
    float4 s4; s4.x = o[4 * i] * inv; s4.y = o[4 * i + 1] * inv;
    s4.z = o[4 * i + 2] * inv; s4.w = o[4 * i + 3] * inv;
    ((float4*)op)[i] = s4;
  }
}

// ---------------- MHA1 output projection (K=64, G=64) ----------------
extern "C" __global__ void __launch_bounds__(256)
k_oproj(const float* attnO, const float* out_w1, const float* out_b1, float* a1) {
  int b  = blockIdx.x >> 4;
  int t0 = (blockIdx.x & 15) << 6;
  __shared__ float al[64 * 65];
  gemm64(attnO + ((size_t)b * TT + t0) * 64, out_w1, out_b1, al, 64, threadIdx.x,
         a1, 64, ((size_t)b * TT + t0) * 64);
}

// ---------------- MHA2: only the last query row matters -> scores s2 + values v2 ----------------
extern "C" __global__ void __launch_bounds__(256)
k_mha2kv(const float* a1, const float* in_w2, const float* in_b2,
         float* s2, float* v2) {
  int b  = blockIdx.x >> 4;
  int t0 = (blockIdx.x & 15) << 6;
  int tid = threadIdx.x;
  __shared__ float a1r[64 * 65];
  __shared__ float q2s[64];
  __shared__ float alast[64];
  if (tid < 64) alast[tid] = a1[((size_t)b * TT + (TT - 1)) * 64 + tid];
  for (int i = tid; i < 4096; i += 256) {
    int r = i >> 6, e = i & 63;
    a1r[r * 65 + e] = a1[((size_t)b * TT + t0 + r) * 64 + e];
  }
  __syncthreads();
  if (tid < 64) {
    float acc = in_b2[tid];
    const float* wr = in_w2 + (size_t)tid * 64;
    #pragma unroll
    for (int e = 0; e < 64; ++e) acc += alast[e] * wr[e];
    q2s[tid] = acc;
  }
  __syncthreads();
  int tt = tid & 63;
  int role = tid >> 6;      // wave-uniform: each wave one role
  const float* ar = &a1r[tt * 65];
  const float scale = 0.17677669529663687f;
  if (role < 2) {
    // head `role`: score for key position t0+tt
    float s = 0.f;
    for (int d = 0; d < 32; ++d) {
      int row = 64 + role * 32 + d;                 // k rows 64..127
      const float* wr = in_w2 + (size_t)row * 64;   // wave-uniform address
      float acc = in_b2[row];
      #pragma unroll
      for (int e = 0; e < 64; ++e) acc += ar[e] * wr[e];
      s += q2s[row - 64] * acc;
    }
    s2[((size_t)b * 2 + role) * TT + t0 + tt] = s * scale;
  } else {
    int half = role - 2;                            // v dims [half*32, half*32+32)
    for (int d = 0; d < 32; ++d) {
      int vd = half * 32 + d;
      int row = 128 + vd;                           // v rows 128..191
      const float* wr = in_w2 + (size_t)row * 64;
      float acc = in_b2[row];
      #pragma unroll
      for (int e = 0; e < 64; ++e) acc += ar[e] * wr[e];
      v2[((size_t)b * TT + t0 + tt) * 64 + vd] = acc;
    }
  }
}

// ---------------- MHA2 softmax+PV, out-proj, final MLP; float32 out + NaN canary ----------------
extern "C" __global__ void __launch_bounds__(256)
k_final(const float* s2, const float* v2,
        const float* out_w2, const float* out_b2,
        const float* w_l, const float* b_l,
        const float* w_l1, const float* b_l1,
        float* out) {
  int b = blockIdx.x;
  int tid = threadIdx.x;
  __shared__ float sm[2 * 1024];
  __shared__ float red[8];
  __shared__ float invl[2];
  __shared__ float opart[4 * 64];
  __shared__ float of[64];
  __shared__ float a2[64];
  __shared__ float hbuf[32];
  __shared__ int bad;
  if (tid == 0) bad = 0;
  for (int i = tid; i < 2048; i += 256) sm[i] = s2[(size_t)b * 2 * TT + i];
  __syncthreads();
  int lane = tid & 63;
  int wid = tid >> 6;
  for (int hh = 0; hh < 2; ++hh) {
    float mx = -1e30f;
    for (int i = tid; i < 1024; i += 256) mx = fmaxf(mx, sm[hh * 1024 + i]);
    #pragma unroll
    for (int off = 32; off > 0; off >>= 1) mx = fmaxf(mx, __shfl_down(mx, off));
    if (lane == 0) red[wid] = mx;
    __syncthreads();
    if (tid == 0) red[4] = fmaxf(fmaxf(red[0], red[1]), fmaxf(red[2], red[3]));
    __syncthreads();
    mx = red[4];
    float s = 0.f;
    for (int i = tid; i < 1024; i += 256) {
      float e = __expf(sm[hh * 1024 + i] - mx);
      sm[hh * 1024 + i] = e;
      s += e;
    }
    #pragma unroll
    for (int off = 32; off > 0; off >>= 1) s += __shfl_down(s, off);
    if (lane == 0) red[wid] = s;
    __syncthreads();
    if (tid == 0) invl[hh] = 1.f / (red[0] + red[1] + red[2] + red[3]);
    __syncthreads();
  }
  {
    int dp = tid & 63;
    int part = tid >> 6;
    int hh = dp >> 5;
    float acc = 0.f;
    for (int t = part * 256; t < part * 256 + 256; ++t)
      acc += sm[hh * 1024 + t] * v2[((size_t)b * TT + t) * 64 + dp];
    opart[part * 64 + dp] = acc;
  }
  __syncthreads();
  if (tid < 64) {
    float o = (opart[tid] + opart[64 + tid] + opart[128 + tid] + opart[192 + tid]) * invl[tid >> 5];
    of[tid] = o;
    if (!finitef(o)) bad = 1;     // NaN canary: distinguishes "ran but NaN" from "never ran"
  }
  __syncthreads();
  if (tid < 64) {
    float acc = out_b2[tid];
    const float* wr = out_w2 + (size_t)tid * 64;
    #pragma unroll
    for (int d = 0; d < 64; ++d) acc += of[d] * wr[d];
    a2[tid] = acc;
  }
  __syncthreads();
  if (tid < 32) {
    float acc = b_l[tid];
    const float* wr = w_l + (size_t)tid * 64;
    #pragma unroll
    for (int e = 0; e < 64; ++e) acc += a2[e] * wr[e];
    hbuf[tid] = fmaxf(acc, 0.f);
  }
  __syncthreads();
  if (tid == 0) {
    float acc = b_l1[0];
    #pragma unroll
    for (int j = 0; j < 32; ++j) acc += hbuf[j] * w_l1[j];
    out[b] = bad ? 777.0f : acc;   // float32 output per reference
  }
}

extern "C" void kernel_launch(void* const* d_in, const int* in_sizes, int n_in,
                              void* d_out, int out_size, void* d_ws, size_t ws_size,
                              hipStream_t stream) {
  const int*   atom_idx  = (const int*)d_in[0];
  const float* bond_dist = (const float*)d_in[1];
  const float* emb       = (const float*)d_in[2];
  const float* w_ih0     = (const float*)d_in[3];
  const float* w_hh0     = (const float*)d_in[4];
  const float* b_ih0     = (const float*)d_in[5];
  const float* b_hh0     = (const float*)d_in[6];
  const float* w_ih1     = (const float*)d_in[7];
  const float* w_hh1     = (const float*)d_in[8];
  const float* b_ih1     = (const float*)d_in[9];
  const float* b_hh1     = (const float*)d_in[10];
  const float* in_w1     = (const float*)d_in[11];
  const float* in_b1     = (const float*)d_in[12];
  const float* out_w1    = (const float*)d_in[13];
  const float* out_b1    = (const float*)d_in[14];
  const float* in_w2     = (const float*)d_in[15];
  const float* in_b2     = (const float*)d_in[16];
  const float* out_w2    = (const float*)d_in[17];
  const float* out_b2    = (const float*)d_in[18];
  const float* w_l       = (const float*)d_in[19];
  const float* b_l       = (const float*)d_in[20];
  const float* w_l1      = (const float*)d_in[21];
  const float* b_l1      = (const float*)d_in[22];

  // Arena plan (84,410,368 B total), all f32:
  //   X @ 0        (50.3 MB): xw0 -> xw1 -> {q,k,v} -> v2
  //   A @ 50331648 (16.8 MB): h0seq -> attnO
  //   B @ 67108864 (16.8 MB): g1 -> a1
  //   D @ 83886080 (0.5 MB):  s2
  char* ws = (char*)d_ws;
  float* X  = (float*)(ws);
  float* A  = (float*)(ws + 50331648);
  float* Bq = (float*)(ws + 67108864);
  float* D  = (float*)(ws + 83886080);
  float* q1 = X;
  float* k1 = X + 4194304;
  float* v1 = X + 8388608;

  k_xw0   <<<dim3(1024), dim3(256), 0, stream>>>(atom_idx, bond_dist, emb, w_ih0, b_ih0, X);
  k_gruseq<<<dim3(64),   dim3(256), 0, stream>>>(X, w_hh0, b_hh0, A);
  k_xw1   <<<dim3(1024), dim3(256), 0, stream>>>(A, w_ih1, b_ih1, X);
  k_gruseq<<<dim3(64),   dim3(256), 0, stream>>>(X, w_hh1, b_hh1, Bq);
  k_qkv   <<<dim3(1024), dim3(256), 0, stream>>>(Bq, in_w1, in_b1, q1, k1, v1);
  k_attn  <<<dim3(512),  dim3(256), 0, stream>>>(q1, k1, v1, A);
  k_oproj <<<dim3(1024), dim3(256), 0, stream>>>(A, out_w1, out_b1, Bq);
  k_mha2kv<<<dim3(1024), dim3(256), 0, stream>>>(Bq, in_w2, in_b2, D, X);
  k_final <<<dim3(64),   dim3(256), 0, stream>>>(D, X, out_w2, out_b2, w_l, b_l, w_l1, b_l1, (float*)d_out);
}